// Round 5
// baseline (371.013 us; speedup 1.0000x reference)
//
#include <hip/hip_runtime.h>
#include <stdint.h>

#define BLOCK          256
#define UNROLL         4
#define MAX_BLOCKS     4096
#define PREPACK_BLOCKS 2048
#define WARM_BLOCKS    2048

typedef float f32x4 __attribute__((ext_vector_type(4)));

// ---------------------------------------------------------------------------
// Pre-pass: fuse gather targets into one 64B record per target point:
//   rec[4j+0..2] = ct rows 0..2,  rec[4j+3] = tar[j]
// k-indexed so both read and write are fully coalesced. Sources are
// non-temporal (read-once); record writes are normal so they stay resident
// in L2/LLC — the pre-pass doubles as the cache warm for maha's gathers.
// ---------------------------------------------------------------------------
__global__ __launch_bounds__(256) void prepack_kernel(
    const f32x4* __restrict__ tar,
    const f32x4* __restrict__ ct,
    f32x4*       __restrict__ rec,
    long n4)                      // n4 = 4*n
{
    const long stride = (long)gridDim.x * 256;
    for (long k = (long)blockIdx.x * 256 + threadIdx.x; k < n4; k += stride) {
        f32x4 v;
        if ((k & 3) == 3) v = __builtin_nontemporal_load(&tar[k >> 2]);
        else              v = __builtin_nontemporal_load(&ct[k]);
        rec[k] = v;
    }
}

// ---------------------------------------------------------------------------
// Fallback warm (used only if workspace is too small for records):
// full-BW float4 sequential read of tar+ct to install them in LLC.
// ---------------------------------------------------------------------------
__global__ __launch_bounds__(256) void llc_warm_kernel(
    const f32x4* __restrict__ tar, long ntar4,
    const f32x4* __restrict__ ct,  long nct4)
{
    const long stride = (long)gridDim.x * 256;
    f32x4 acc = {0.f, 0.f, 0.f, 0.f};
    for (long k = (long)blockIdx.x * 256 + threadIdx.x; k < nct4; k += stride)
        acc += ct[k];
    for (long k = (long)blockIdx.x * 256 + threadIdx.x; k < ntar4; k += stride)
        acc += tar[k];
    asm volatile("" :: "v"(acc.x), "v"(acc.y), "v"(acc.z), "v"(acc.w));
}

// ---------------------------------------------------------------------------
// maha core. Streams (idx/src/cs) non-temporal; gather hits the fused
// 64B record (one sector per point).
// ---------------------------------------------------------------------------
__device__ __forceinline__ float gicp_math(
    const f32x4 s, const f32x4 tp,
    const f32x4 c0, const f32x4 c1, const f32x4 c2,
    const f32x4 d0, const f32x4 d1, const f32x4 d2,
    const float t00, const float t01, const float t02,
    const float t10, const float t11, const float t12,
    const float t20, const float t21, const float t22,
    const float t30, const float t31, const float t32)
{
    const float ts0 = s.x * t00 + s.y * t10 + s.z * t20 + s.w * t30;
    const float ts1 = s.x * t01 + s.y * t11 + s.z * t21 + s.w * t31;
    const float ts2 = s.x * t02 + s.y * t12 + s.z * t22 + s.w * t32;
    const float r0 = tp.x - ts0;
    const float r1 = tp.y - ts1;
    const float r2 = tp.z - ts2;

    const float u00 = t00*c0.x + t01*c1.x + t02*c2.x;
    const float u01 = t00*c0.y + t01*c1.y + t02*c2.y;
    const float u02 = t00*c0.z + t01*c1.z + t02*c2.z;
    const float u10 = t10*c0.x + t11*c1.x + t12*c2.x;
    const float u11 = t10*c0.y + t11*c1.y + t12*c2.y;
    const float u12 = t10*c0.z + t11*c1.z + t12*c2.z;
    const float u20 = t20*c0.x + t21*c1.x + t22*c2.x;
    const float u21 = t20*c0.y + t21*c1.y + t22*c2.y;
    const float u22 = t20*c0.z + t21*c1.z + t22*c2.z;

    const float tc00 = u00*t00 + u01*t01 + u02*t02;
    const float tc01 = u00*t10 + u01*t11 + u02*t12;
    const float tc02 = u00*t20 + u01*t21 + u02*t22;
    const float tc11 = u10*t10 + u11*t11 + u12*t12;
    const float tc12 = u10*t20 + u11*t21 + u12*t22;
    const float tc22 = u20*t20 + u21*t21 + u22*t22;

    const float a = d0.x + tc00;
    const float b = d0.y + tc01;
    const float c = d0.z + tc02;
    const float d = d1.y + tc11;
    const float e = d1.z + tc12;
    const float f = d2.z + tc22;

    const float A00 = d * f - e * e;
    const float A01 = c * e - b * f;
    const float A02 = b * e - c * d;
    const float A11 = a * f - c * c;
    const float A12 = b * c - a * e;
    const float A22 = a * d - b * b;

    const float det = a * A00 + b * A01 + c * A02;
    const float num = r0 * r0 * A00 + r1 * r1 * A11 + r2 * r2 * A22
                    + 2.0f * (r0 * r1 * A01 + r0 * r2 * A02 + r1 * r2 * A12);
    return num / det;
}

__device__ __forceinline__ float gicp_point_rec(
    int i,
    const float t00, const float t01, const float t02,
    const float t10, const float t11, const float t12,
    const float t20, const float t21, const float t22,
    const float t30, const float t31, const float t32,
    const f32x4* __restrict__ src, const f32x4* __restrict__ cs,
    const f32x4* __restrict__ rec, const int* __restrict__ idx)
{
    const int   j  = __builtin_nontemporal_load(&idx[i]);
    const f32x4 s  = __builtin_nontemporal_load(&src[i]);

    const size_t bj = (size_t)j * 4;
    const f32x4 d0 = rec[bj + 0];      // one 64B sector for the whole gather
    const f32x4 d1 = rec[bj + 1];
    const f32x4 d2 = rec[bj + 2];
    const f32x4 tp = rec[bj + 3];

    const size_t bi = (size_t)i * 4;
    const f32x4 c0 = __builtin_nontemporal_load(&cs[bi + 0]);
    const f32x4 c1 = __builtin_nontemporal_load(&cs[bi + 1]);
    const f32x4 c2 = __builtin_nontemporal_load(&cs[bi + 2]);

    return gicp_math(s, tp, c0, c1, c2, d0, d1, d2,
                     t00,t01,t02,t10,t11,t12,t20,t21,t22,t30,t31,t32);
}

__device__ __forceinline__ float gicp_point_dir(
    int i,
    const float t00, const float t01, const float t02,
    const float t10, const float t11, const float t12,
    const float t20, const float t21, const float t22,
    const float t30, const float t31, const float t32,
    const f32x4* __restrict__ src, const f32x4* __restrict__ tar,
    const f32x4* __restrict__ cs,  const f32x4* __restrict__ ct,
    const int*   __restrict__ idx)
{
    const int   j  = __builtin_nontemporal_load(&idx[i]);
    const f32x4 s  = __builtin_nontemporal_load(&src[i]);
    const f32x4 tp = tar[j];
    const size_t bj = (size_t)j * 4;
    const f32x4 d0 = ct[bj + 0];
    const f32x4 d1 = ct[bj + 1];
    const f32x4 d2 = ct[bj + 2];
    const size_t bi = (size_t)i * 4;
    const f32x4 c0 = __builtin_nontemporal_load(&cs[bi + 0]);
    const f32x4 c1 = __builtin_nontemporal_load(&cs[bi + 1]);
    const f32x4 c2 = __builtin_nontemporal_load(&cs[bi + 2]);
    return gicp_math(s, tp, c0, c1, c2, d0, d1, d2,
                     t00,t01,t02,t10,t11,t12,t20,t21,t22,t30,t31,t32);
}

#define TLOAD  const float t00 = T[0],  t01 = T[1],  t02 = T[2]; \
               const float t10 = T[4],  t11 = T[5],  t12 = T[6]; \
               const float t20 = T[8],  t21 = T[9],  t22 = T[10]; \
               const float t30 = T[12], t31 = T[13], t32 = T[14];

__global__ __launch_bounds__(BLOCK) void gicp_maha_rec_kernel(
    const float* __restrict__ T,
    const f32x4* __restrict__ src,
    const f32x4* __restrict__ cs,
    const f32x4* __restrict__ rec,
    const int*   __restrict__ idx,
    float*       __restrict__ partial,
    int n)
{
    TLOAD
    const int stride = gridDim.x * BLOCK;
    const int step   = stride * UNROLL;

    float local = 0.0f;
    for (int base = blockIdx.x * BLOCK + threadIdx.x; base < n; base += step) {
        if (base + 3 * stride < n) {
            float v0 = gicp_point_rec(base,            t00,t01,t02,t10,t11,t12,t20,t21,t22,t30,t31,t32, src,cs,rec,idx);
            float v1 = gicp_point_rec(base +   stride, t00,t01,t02,t10,t11,t12,t20,t21,t22,t30,t31,t32, src,cs,rec,idx);
            float v2 = gicp_point_rec(base + 2*stride, t00,t01,t02,t10,t11,t12,t20,t21,t22,t30,t31,t32, src,cs,rec,idx);
            float v3 = gicp_point_rec(base + 3*stride, t00,t01,t02,t10,t11,t12,t20,t21,t22,t30,t31,t32, src,cs,rec,idx);
            local += (v0 + v1) + (v2 + v3);
        } else {
            #pragma unroll
            for (int k = 0; k < UNROLL; ++k) {
                int i = base + k * stride;
                const float m = (i < n) ? 1.0f : 0.0f;
                i = (i < n) ? i : (n - 1);
                local += m * gicp_point_rec(i, t00,t01,t02,t10,t11,t12,t20,t21,t22,t30,t31,t32, src,cs,rec,idx);
            }
        }
    }

    for (int off = 32; off > 0; off >>= 1)
        local += __shfl_down(local, off, 64);
    __shared__ float wsum[BLOCK / 64];
    const int wave = threadIdx.x >> 6;
    if ((threadIdx.x & 63) == 0) wsum[wave] = local;
    __syncthreads();
    if (threadIdx.x == 0) {
        float s = wsum[0];
        #pragma unroll
        for (int w = 1; w < BLOCK / 64; ++w) s += wsum[w];
        partial[blockIdx.x] = s;
    }
}

__global__ __launch_bounds__(BLOCK) void gicp_maha_dir_kernel(
    const float* __restrict__ T,
    const f32x4* __restrict__ src,
    const f32x4* __restrict__ tar,
    const f32x4* __restrict__ cs,
    const f32x4* __restrict__ ct,
    const int*   __restrict__ idx,
    float*       __restrict__ partial,
    int n)
{
    TLOAD
    const int stride = gridDim.x * BLOCK;
    const int step   = stride * UNROLL;

    float local = 0.0f;
    for (int base = blockIdx.x * BLOCK + threadIdx.x; base < n; base += step) {
        if (base + 3 * stride < n) {
            float v0 = gicp_point_dir(base,            t00,t01,t02,t10,t11,t12,t20,t21,t22,t30,t31,t32, src,tar,cs,ct,idx);
            float v1 = gicp_point_dir(base +   stride, t00,t01,t02,t10,t11,t12,t20,t21,t22,t30,t31,t32, src,tar,cs,ct,idx);
            float v2 = gicp_point_dir(base + 2*stride, t00,t01,t02,t10,t11,t12,t20,t21,t22,t30,t31,t32, src,tar,cs,ct,idx);
            float v3 = gicp_point_dir(base + 3*stride, t00,t01,t02,t10,t11,t12,t20,t21,t22,t30,t31,t32, src,tar,cs,ct,idx);
            local += (v0 + v1) + (v2 + v3);
        } else {
            #pragma unroll
            for (int k = 0; k < UNROLL; ++k) {
                int i = base + k * stride;
                const float m = (i < n) ? 1.0f : 0.0f;
                i = (i < n) ? i : (n - 1);
                local += m * gicp_point_dir(i, t00,t01,t02,t10,t11,t12,t20,t21,t22,t30,t31,t32, src,tar,cs,ct,idx);
            }
        }
    }

    for (int off = 32; off > 0; off >>= 1)
        local += __shfl_down(local, off, 64);
    __shared__ float wsum[BLOCK / 64];
    const int wave = threadIdx.x >> 6;
    if ((threadIdx.x & 63) == 0) wsum[wave] = local;
    __syncthreads();
    if (threadIdx.x == 0) {
        float s = wsum[0];
        #pragma unroll
        for (int w = 1; w < BLOCK / 64; ++w) s += wsum[w];
        partial[blockIdx.x] = s;
    }
}

__global__ __launch_bounds__(256) void gicp_finalize_kernel(
    const float* __restrict__ partial, float* __restrict__ out,
    double scale, int nblocks)
{
    double s = 0.0;
    for (int k = threadIdx.x; k < nblocks; k += 256)
        s += (double)partial[k];
    for (int off = 32; off > 0; off >>= 1)
        s += __shfl_down(s, off, 64);
    __shared__ double wsum[4];
    const int wave = threadIdx.x >> 6;
    if ((threadIdx.x & 63) == 0) wsum[wave] = s;
    __syncthreads();
    if (threadIdx.x == 0)
        out[0] = (float)((wsum[0] + wsum[1] + wsum[2] + wsum[3]) * scale);
}

extern "C" void kernel_launch(void* const* d_in, const int* in_sizes, int n_in,
                              void* d_out, int out_size, void* d_ws, size_t ws_size,
                              hipStream_t stream) {
    const float* T   = (const float*)d_in[0];
    const f32x4* src = (const f32x4*)d_in[1];
    const f32x4* tar = (const f32x4*)d_in[2];
    const f32x4* cs  = (const f32x4*)d_in[3];
    const f32x4* ct  = (const f32x4*)d_in[4];
    const int*   idx = (const int*)d_in[5];
    const int n = in_sizes[1] / 4;          // src_points is (N,4) floats

    int nblocks = (n + BLOCK * UNROLL - 1) / (BLOCK * UNROLL);
    if (nblocks < 1) nblocks = 1;
    if (nblocks > MAX_BLOCKS) nblocks = MAX_BLOCKS;

    // workspace layout: [0, 16KB) partials, [16KB, 16KB + 64*n) records
    const size_t rec_off   = 16384;
    const size_t rec_bytes = (size_t)n * 64;
    float* partial = (float*)d_ws;
    const int ws_cap = MAX_BLOCKS;  // partial region holds 4096 floats
    if (nblocks > ws_cap) nblocks = ws_cap;

    if (ws_size >= rec_off + rec_bytes) {
        f32x4* rec = (f32x4*)((char*)d_ws + rec_off);
        prepack_kernel<<<PREPACK_BLOCKS, 256, 0, stream>>>(tar, ct, rec,
                                                           (long)n * 4);
        gicp_maha_rec_kernel<<<nblocks, BLOCK, 0, stream>>>(T, src, cs, rec,
                                                            idx, partial, n);
    } else {
        // fallback: full-BW sequential warm of the gather targets, then direct
        llc_warm_kernel<<<WARM_BLOCKS, 256, 0, stream>>>(
            tar, (long)in_sizes[2] / 4, ct, (long)in_sizes[4] / 4);
        gicp_maha_dir_kernel<<<nblocks, BLOCK, 0, stream>>>(T, src, tar, cs,
                                                            ct, idx, partial, n);
    }
    gicp_finalize_kernel<<<1, 256, 0, stream>>>(partial, (float*)d_out,
                                                0.5 / (double)n, nblocks);
}